// Round 1
// baseline (95.038 us; speedup 1.0000x reference)
//
#include <hip/hip_runtime.h>
#include <hip/hip_cooperative_groups.h>

namespace cg = cooperative_groups;

// SmoothAP: B=32, N=1024
// ap[b] = (1/npos) * sum_i m_i * (1 + sum_j sig_ij*m_j) / (1 + sum_j sig_ij)
// sig_ij = 1/(1+exp(clamp(1000*(d_i-d_j), -50, 50))), diagonal excluded.
//
// Fused single cooperative kernel: phase 1 = thread-per-row-i, j split S ways
// across blocks (zero cross-lane work in the hot loop), partials to workspace;
// grid.sync(); phase 2 = first 32 blocks combine partials (identical code +
// summation order to the old second kernel -> bit-identical output).
//
// Clamp dropped: unclamped exp2 saturates to inf/0 -> sig in {0,1}; differs
// from the clamped reference by <= 1.93e-22 per element (~1e-21 relative on
// R>=1), far below f32 ulp of the output. Diagonal still sig(0)=0.5 exactly.

#define BB 32
#define NN 1024
#define S  16
#define JR (NN / S)        /* 64 j's per block */
#define BLOCK 256
#define IPT (NN / BLOCK)   /* 4 rows i per thread */

#define C_LOG2E 1442.6950408889634f   /* 1000 * log2(e) */

__global__ __launch_bounds__(BLOCK, 2) void smoothap_fused(
    const float* __restrict__ sim, const int* __restrict__ mask,
    float* __restrict__ psum, float* __restrict__ psump,
    float* __restrict__ out)
{
    __shared__ float2 s_jm[JR];   // {d_j * C, m_j}
    __shared__ float  s_r[8];

    const int b   = blockIdx.x / S;
    const int js  = blockIdx.x % S;
    const int j0  = js * JR;
    const int tid = threadIdx.x;

    // ---------------- phase 1: partial row sums over this block's j-range ----
    if (tid < JR) {
        float sj = sim[b * NN + j0 + tid];
        float mj = (mask[b * (NN + 1) + 1 + j0 + tid] != 0) ? 1.0f : 0.0f;
        s_jm[tid] = make_float2(sj * C_LOG2E, mj);
    }
    __syncthreads();

    float diC[IPT], sum[IPT], sump[IPT];
    #pragma unroll
    for (int k = 0; k < IPT; ++k) {
        diC[k]  = sim[b * NN + tid + k * BLOCK] * C_LOG2E;
        sum[k]  = 0.0f;
        sump[k] = 0.0f;
    }

    #pragma unroll 4
    for (int j = 0; j < JR; ++j) {
        const float2 jm = s_jm[j];           // broadcast LDS read
        #pragma unroll
        for (int k = 0; k < IPT; ++k) {
            float t = diC[k] - jm.x;                 // (d_i-d_j)*1000*log2e
            float p   = __builtin_amdgcn_exp2f(t);   // saturates: inf / 0
            float sig = __builtin_amdgcn_rcpf(1.0f + p);
            sum[k] += sig;
            sump[k] = fmaf(sig, jm.y, sump[k]);
        }
    }

    #pragma unroll
    for (int k = 0; k < IPT; ++k) {
        const int i = tid + k * BLOCK;
        if (i >= j0 && i < j0 + JR) {        // diagonal was included as sig(0)=0.5
            sum[k]  -= 0.5f;
            sump[k] -= 0.5f * s_jm[i - j0].y;
        }
        psum [(b * S + js) * NN + i] = sum[k];
        psump[(b * S + js) * NN + i] = sump[k];
    }

    // ---------------- grid-wide barrier (agent-scope release/acquire) --------
    cg::this_grid().sync();

    // ---------------- phase 2: 32 blocks combine partials (bit-identical) ----
    if (blockIdx.x >= BB) return;
    const int fb = blockIdx.x;

    float acc = 0.0f, npos = 0.0f;
    #pragma unroll
    for (int k = 0; k < IPT; ++k) {
        const int i = tid + k * BLOCK;
        float R = 1.0f, Rp = 1.0f;
        #pragma unroll
        for (int s = 0; s < S; ++s) {
            R  += psum [(fb * S + s) * NN + i];   // coalesced over tid
            Rp += psump[(fb * S + s) * NN + i];
        }
        float mi = (mask[fb * (NN + 1) + 1 + i] != 0) ? 1.0f : 0.0f;
        acc  += mi * __fdividef(Rp, R);
        npos += mi;
    }

    #pragma unroll
    for (int off = 32; off > 0; off >>= 1) {
        acc  += __shfl_down(acc,  off, 64);
        npos += __shfl_down(npos, off, 64);
    }
    const int wave = tid >> 6;
    if ((tid & 63) == 0) { s_r[wave] = acc; s_r[4 + wave] = npos; }
    __syncthreads();
    if (tid == 0) {
        float a = 0.0f, n = 0.0f;
        #pragma unroll
        for (int w = 0; w < 4; ++w) { a += s_r[w]; n += s_r[4 + w]; }
        out[fb] = a / n;
    }
}

extern "C" void kernel_launch(void* const* d_in, const int* in_sizes, int n_in,
                              void* d_out, int out_size, void* d_ws, size_t ws_size,
                              hipStream_t stream) {
    const float* sim = (const float*)d_in[0];
    const int* mask  = (const int*)d_in[1];
    float* out       = (float*)d_out;

    float* psum  = (float*)d_ws;                       // BB*S*NN floats = 2 MB
    float* psump = (float*)d_ws + (size_t)BB * S * NN; // 2 MB more

    void* args[] = { (void*)&sim, (void*)&mask, (void*)&psum, (void*)&psump,
                     (void*)&out };
    hipLaunchCooperativeKernel((const void*)smoothap_fused, dim3(BB * S),
                               dim3(BLOCK), args, 0, stream);
}

// Round 2
// 22.292 us; speedup vs baseline: 4.2633x; 4.2633x over previous
//
#include <hip/hip_runtime.h>

// SmoothAP: B=32, N=1024
// ap[b] = (1/npos) * sum_i m_i * (1 + sum_j sig_ij*m_j) / (1 + sum_j sig_ij)
// sig_ij = 1/(1+exp(1000*(d_i-d_j))), diagonal excluded. (Clamp dropped:
// unclamped exp2 saturates to inf/0 -> sig in {0,1}; error <= 2e-22/element,
// verified absmax 0.0 in earlier round.)
//
// Row-split structure: each block owns 64 COMPLETE rows of one batch and all
// 1024 j (staged in 8 KB LDS). 4 waves each cover a 256-j quarter -> hot-loop
// LDS read is a wave-uniform broadcast (no conflicts). Rows are finished
// in-block (R, Rp, mi*Rp/R, npos) and one atomicAdd per block lands in out[b].
// Kills the 4 MB partial-sum round trip AND the second dispatch of the old
// j-split design. out[] zeroed by a captured hipMemsetAsync node.

#define BB 32
#define NN 1024
#define RS 16              /* row-splits per batch */
#define RC (NN / RS)       /* 64 rows per block */
#define BLOCK 256
#define JW (NN / 4)        /* 256 j per wave (4 waves per block) */

#define C_LOG2E 1442.6950408889634f   /* 1000 * log2(e) */

__global__ __launch_bounds__(BLOCK) void smoothap_rows(
    const float* __restrict__ sim, const int* __restrict__ mask,
    float* __restrict__ out)
{
    __shared__ float2 s_jm[NN];         // 8 KB: {d_j * C, m_j}
    __shared__ float2 s_red[4 * RC];    // 2 KB: per-wave row partials

    const int b   = blockIdx.x / RS;
    const int rs  = blockIdx.x % RS;
    const int i0  = rs * RC;
    const int tid = threadIdx.x;
    const int r   = tid & 63;           // row within block (lane)
    const int w   = tid >> 6;           // wave id = j-quarter

    // stage the whole batch's {d_j*C, m_j}
    #pragma unroll
    for (int k = 0; k < NN / BLOCK; ++k) {
        const int j = tid + k * BLOCK;
        float sj = sim[b * NN + j];
        float mj = (mask[b * (NN + 1) + 1 + j] != 0) ? 1.0f : 0.0f;
        s_jm[j] = make_float2(sj * C_LOG2E, mj);
    }
    __syncthreads();

    const int   ig  = i0 + r;           // global row index within batch
    const float diC = s_jm[ig].x;       // own d_i*C straight from LDS

    float sum = 0.0f, sump = 0.0f;
    const int jbase = w * JW;
    #pragma unroll 8
    for (int jj = 0; jj < JW; ++jj) {
        const float2 jm = s_jm[jbase + jj];      // broadcast (all lanes same j)
        float t   = diC - jm.x;                  // (d_i-d_j)*1000*log2e
        float p   = __builtin_amdgcn_exp2f(t);   // saturates inf/0, no clamp
        float sig = __builtin_amdgcn_rcpf(1.0f + p);
        sum += sig;
        sump = fmaf(sig, jm.y, sump);
    }

    // diagonal j==ig was counted as sig(0)=0.5; wave-uniform branch
    if ((ig >> 8) == w) {
        sum  -= 0.5f;
        sump -= 0.5f * s_jm[ig].y;
    }

    s_red[w * RC + r] = make_float2(sum, sump);
    __syncthreads();

    // wave 0 finishes the 64 rows: combine quarters, divide, reduce, atomic
    if (tid < RC) {
        float S = 0.0f, Sp = 0.0f;
        #pragma unroll
        for (int q = 0; q < 4; ++q) {
            float2 v = s_red[q * RC + tid];
            S += v.x; Sp += v.y;
        }
        const float mi = s_jm[i0 + tid].y;
        float c = mi * __fdividef(1.0f + Sp, 1.0f + S);

        float np = 0.0f;                 // npos = sum over all 1024 mask bits
        #pragma unroll
        for (int k = 0; k < NN / 64; ++k) np += s_jm[tid + k * 64].y;

        #pragma unroll
        for (int off = 32; off > 0; off >>= 1) {
            c  += __shfl_down(c,  off, 64);
            np += __shfl_down(np, off, 64);
        }
        if (tid == 0) atomicAdd(&out[b], c / np);
    }
}

extern "C" void kernel_launch(void* const* d_in, const int* in_sizes, int n_in,
                              void* d_out, int out_size, void* d_ws, size_t ws_size,
                              hipStream_t stream) {
    const float* sim = (const float*)d_in[0];
    const int* mask  = (const int*)d_in[1];
    float* out       = (float*)d_out;

    hipMemsetAsync(out, 0, BB * sizeof(float), stream);
    smoothap_rows<<<BB * RS, BLOCK, 0, stream>>>(sim, mask, out);
}

// Round 3
// 16.056 us; speedup vs baseline: 5.9192x; 1.3884x over previous
//
#include <hip/hip_runtime.h>

// SmoothAP: B=32, N=1024
// ap[b] = (1/npos) * sum_i m_i * (1 + sum_j sig_ij*m_j) / (1 + sum_j sig_ij)
// sig_ij = 1/(1+exp(1000*(d_i-d_j))), diagonal excluded. Clamp dropped:
// unclamped exp2 saturates to inf/0 -> sig in {0,1} exactly; per-element error
// <= 2e-22 vs clamped reference (verified absmax 0.0 in earlier rounds).
//
// Structure (R3): row-split blocks finish their 64 rows completely and write
// ONE float2 {c_partial, npos} each to a distinct ws slot (plain store -> no
// zeroing of poisoned ws needed, no atomics). A minimal 1-block second kernel
// combines 512 float2 -> 32 outputs. Lessons: grid.sync costs ~65us (R1);
// memset-dispatch + atomics is WORSE than a real second kernel (R2); so the
// floor structure is 2 dispatches with near-zero traffic between them.
//
// Hot kernel: 8 waves/block (512 thr), each wave covers a 128-j strip of the
// LDS-staged batch -> 4096 waves = 4 waves/SIMD for latency hiding; hot-loop
// LDS read is wave-uniform broadcast (zero bank conflicts).

#define BB 32
#define NN 1024
#define RS 16              /* row-splits per batch */
#define RC 64              /* rows per block (= lanes) */
#define BLOCK 512          /* 8 waves */
#define WPB 8
#define JW (NN / WPB)      /* 128 j per wave */

#define C_LOG2E 1442.6950408889634f   /* 1000 * log2(e) */

__global__ __launch_bounds__(BLOCK) void smoothap_rows(
    const float* __restrict__ sim, const int* __restrict__ mask,
    float2* __restrict__ part)
{
    __shared__ float2 s_jm[NN];         // 8 KB: {d_j * C, m_j}
    __shared__ float2 s_red[WPB * RC];  // 4 KB: per-wave row partials

    const int b   = blockIdx.x / RS;
    const int rs  = blockIdx.x % RS;
    const int i0  = rs * RC;
    const int tid = threadIdx.x;
    const int r   = tid & 63;           // row within block (lane)
    const int w   = tid >> 6;           // wave id = j-strip

    // stage the whole batch's {d_j*C, m_j}
    #pragma unroll
    for (int k = 0; k < NN / BLOCK; ++k) {
        const int j = tid + k * BLOCK;
        float sj = sim[b * NN + j];
        float mj = (mask[b * (NN + 1) + 1 + j] != 0) ? 1.0f : 0.0f;
        s_jm[j] = make_float2(sj * C_LOG2E, mj);
    }
    __syncthreads();

    const int   ig  = i0 + r;           // global row index within batch
    const float diC = s_jm[ig].x;       // own d_i*C from LDS

    float sum = 0.0f, sump = 0.0f;
    const int jbase = w * JW;
    #pragma unroll 8
    for (int jj = 0; jj < JW; ++jj) {
        const float2 jm = s_jm[jbase + jj];      // broadcast (all lanes same j)
        float t   = diC - jm.x;                  // (d_i-d_j)*1000*log2e
        float p   = __builtin_amdgcn_exp2f(t);   // saturates inf/0, no clamp
        float sig = __builtin_amdgcn_rcpf(1.0f + p);
        sum += sig;
        sump = fmaf(sig, jm.y, sump);
    }

    // diagonal j==ig was counted as sig(0)=0.5; wave-uniform branch
    if ((ig >> 7) == w) {
        sum  -= 0.5f;
        sump -= 0.5f * s_jm[ig].y;
    }

    s_red[w * RC + r] = make_float2(sum, sump);
    __syncthreads();

    // wave 0 finishes the 64 rows: combine strips, divide, reduce, store slot
    if (tid < RC) {
        float S = 0.0f, Sp = 0.0f;
        #pragma unroll
        for (int q = 0; q < WPB; ++q) {
            float2 v = s_red[q * RC + tid];
            S += v.x; Sp += v.y;
        }
        const float mi = s_jm[i0 + tid].y;
        float c = mi * __fdividef(1.0f + Sp, 1.0f + S);

        float np = 0.0f;                 // npos = sum over all 1024 mask bits
        #pragma unroll
        for (int k = 0; k < NN / 64; ++k) np += s_jm[tid + k * 64].y;

        #pragma unroll
        for (int off = 32; off > 0; off >>= 1) {
            c  += __shfl_down(c,  off, 64);
            np += __shfl_down(np, off, 64);
        }
        if (tid == 0) part[blockIdx.x] = make_float2(c, np);
    }
}

// 1 block, 512 threads: slot t -> batch t>>4; width-16 shuffle reduce.
__global__ __launch_bounds__(BB * RS) void smoothap_combine(
    const float2* __restrict__ part, float* __restrict__ out)
{
    const int t = threadIdx.x;
    float2 v = part[t];
    float c = v.x;
    #pragma unroll
    for (int off = 8; off > 0; off >>= 1)
        c += __shfl_down(c, off, 16);   // batches are 16-aligned segments
    if ((t & 15) == 0) out[t >> 4] = c / v.y;
}

extern "C" void kernel_launch(void* const* d_in, const int* in_sizes, int n_in,
                              void* d_out, int out_size, void* d_ws, size_t ws_size,
                              hipStream_t stream) {
    const float* sim = (const float*)d_in[0];
    const int* mask  = (const int*)d_in[1];
    float* out       = (float*)d_out;
    float2* part     = (float2*)d_ws;   // BB*RS float2 = 4 KB

    smoothap_rows<<<BB * RS, BLOCK, 0, stream>>>(sim, mask, part);
    smoothap_combine<<<1, BB * RS, 0, stream>>>(part, out);
}

// Round 4
// 15.066 us; speedup vs baseline: 6.3083x; 1.0657x over previous
//
#include <hip/hip_runtime.h>

// SmoothAP: B=32, N=1024
// ap[b] = (1/npos) * sum_i m_i * (1 + sum_j sig_ij*m_j) / (1 + sum_j sig_ij)
// sig_ij = 1/(1+exp(1000*(d_i-d_j))), diagonal excluded. Clamp dropped:
// unclamped exp2 saturates to inf/0 -> sig in {0,1} exactly; per-element error
// <= 2e-22 vs clamped reference (verified absmax 0.0 in earlier rounds).
//
// R4: SINGLE dispatch. Lessons: grid.sync ~65us (R1); memset+atomics worse
// than a 2nd kernel (R2); 2-dispatch floor was ~16us (R3) with ~2-4us spent
// on the second node. Here each row-split block writes a SELF-VALIDATING
// 64-bit slot {hi=bits(c), lo=bits(c)^KEY} via agent-scope atomic store (any
// uniform poison fails hi==lo^KEY, so no zero-init needed), then all 16
// sibling blocks of a batch poll the batch's 16 slots with agent-scope atomic
// loads (XCD L2s are not coherent -> plain loads could be stale) and
// redundantly compute the bitwise-identical ap[b] (same shuffle tree as R3's
// combine kernel -> absmax stays 0.0). Benign identical-value race on out[b].
// Deadlock-free: store precedes poll; all 4096 waves co-resident (cap 8192).

#define BB 32
#define NN 1024
#define RS 16              /* row-splits per batch = slots per batch */
#define RC 64              /* rows per block (= lanes) */
#define BLOCK 512          /* 8 waves */
#define WPB 8
#define JW (NN / WPB)      /* 128 j per wave */

#define C_LOG2E 1442.6950408889634f   /* 1000 * log2(e) */
#define VKEY 0xA5A5A5A5u

typedef unsigned long long u64;

__global__ __launch_bounds__(BLOCK) void smoothap_onepass(
    const float* __restrict__ sim, const int* __restrict__ mask,
    u64* __restrict__ slots, float* __restrict__ out)
{
    __shared__ float2 s_jm[NN];         // 8 KB: {d_j * C, m_j}
    __shared__ float2 s_red[WPB * RC];  // 4 KB: per-wave row partials

    const int b   = blockIdx.x / RS;
    const int rs  = blockIdx.x % RS;
    const int i0  = rs * RC;
    const int tid = threadIdx.x;
    const int r   = tid & 63;           // row within block (lane)
    const int w   = tid >> 6;           // wave id = j-strip

    // stage the whole batch's {d_j*C, m_j}
    #pragma unroll
    for (int k = 0; k < NN / BLOCK; ++k) {
        const int j = tid + k * BLOCK;
        float sj = sim[b * NN + j];
        float mj = (mask[b * (NN + 1) + 1 + j] != 0) ? 1.0f : 0.0f;
        s_jm[j] = make_float2(sj * C_LOG2E, mj);
    }
    __syncthreads();

    const int   ig  = i0 + r;           // global row index within batch
    const float diC = s_jm[ig].x;       // own d_i*C from LDS

    float sum = 0.0f, sump = 0.0f;
    const int jbase = w * JW;
    #pragma unroll 8
    for (int jj = 0; jj < JW; ++jj) {
        const float2 jm = s_jm[jbase + jj];      // broadcast (all lanes same j)
        float t   = diC - jm.x;                  // (d_i-d_j)*1000*log2e
        float p   = __builtin_amdgcn_exp2f(t);   // saturates inf/0, no clamp
        float sig = __builtin_amdgcn_rcpf(1.0f + p);
        sum += sig;
        sump = fmaf(sig, jm.y, sump);
    }

    // diagonal j==ig was counted as sig(0)=0.5; wave-uniform branch
    if ((ig >> 7) == w) {
        sum  -= 0.5f;
        sump -= 0.5f * s_jm[ig].y;
    }

    s_red[w * RC + r] = make_float2(sum, sump);
    __syncthreads();

    if (tid >= RC) return;              // waves 1..7 done; wave 0 finishes

    // combine strips, per-row divide, 64-lane reduce (identical to R3)
    float S = 0.0f, Sp = 0.0f;
    #pragma unroll
    for (int q = 0; q < WPB; ++q) {
        float2 v = s_red[q * RC + tid];
        S += v.x; Sp += v.y;
    }
    const float mi = s_jm[i0 + tid].y;
    float c = mi * __fdividef(1.0f + Sp, 1.0f + S);

    float np = 0.0f;                     // npos = sum over all 1024 mask bits
    #pragma unroll
    for (int k = 0; k < NN / 64; ++k) np += s_jm[tid + k * 64].y;

    #pragma unroll
    for (int off = 32; off > 0; off >>= 1) {
        c  += __shfl_down(c,  off, 64);
        np += __shfl_down(np, off, 64);
    }
    // tid 0 now holds this block's partial c and the batch's np

    u64* bslots = slots + b * RS;
    if (tid == 0) {
        unsigned cb = __float_as_uint(c);
        u64 v = ((u64)cb << 32) | (u64)(cb ^ VKEY);
        __hip_atomic_store(&bslots[rs], v, __ATOMIC_RELAXED,
                           __HIP_MEMORY_SCOPE_AGENT);
    }

    // poll all 16 sibling slots (lanes 0..15), agent scope, self-validating
    bool ok = (tid >= RS);
    u64 v = 0;
    while (!__all(ok)) {
        if (!ok) {
            v = __hip_atomic_load(&bslots[tid], __ATOMIC_RELAXED,
                                  __HIP_MEMORY_SCOPE_AGENT);
            ok = ((unsigned)(v >> 32)) == (((unsigned)v) ^ VKEY);
            if (!ok) __builtin_amdgcn_s_sleep(1);
        }
    }

    // same width-16 shuffle tree as R3's combine kernel -> bitwise identical
    float cp = (tid < RS) ? __uint_as_float((unsigned)(v >> 32)) : 0.0f;
    #pragma unroll
    for (int off = 8; off > 0; off >>= 1)
        cp += __shfl_down(cp, off, 16);
    if (tid == 0) out[b] = cp / np;      // identical value from all 16 writers
}

extern "C" void kernel_launch(void* const* d_in, const int* in_sizes, int n_in,
                              void* d_out, int out_size, void* d_ws, size_t ws_size,
                              hipStream_t stream) {
    const float* sim = (const float*)d_in[0];
    const int* mask  = (const int*)d_in[1];
    float* out       = (float*)d_out;
    u64* slots       = (u64*)d_ws;      // BB*RS u64 = 4 KB

    smoothap_onepass<<<BB * RS, BLOCK, 0, stream>>>(sim, mask, slots, out);
}